// Round 1
// 232.791 us; speedup vs baseline: 1.0004x; 1.0004x over previous
//
#include <hip/hip_runtime.h>

// Problem: B=4, S=4096, H=16, D=128 -> C=2048, K=4. All fp32.
// out[b,h,s,d] = silu( bias[c] + sum_{k=0..3} w[c,k] * x[b, s-3+k, c] ), c = h*128+d
// x layout: [B,S,C] contiguous; causal (zero left-pad).
//
// Round-4 theory: VGPR_Count=36 proved the register-batched loads never
// materialized (44 payload VGPRs would be live); compiler re-pipelined to ~2-3
// loads in flight with per-iteration vmcnt waits that also count trailing
// stores -> ~full HBM latency per output row -> 34% HBM BW.
// Fix: structural MLP via global_load_lds (width 16). Each wave issues 11 async
// 1KB global->LDS loads (data never in VGPRs -> compiler can't sink them), one
// vmcnt(0)+barrier per block amortized over 44KB, stores never waited on.
// LDS 44KB -> 3 blocks/CU resident -> ~132KB reads in flight per CU.

constexpr int Bb = 4, Ss = 4096, Hh = 16, Dd = 128, Cc = 2048, Kk = 4;
constexpr int SEQ  = 8;            // s positions per block
constexpr int CPB  = 1024;         // channels per block (256 threads x 4)
constexpr int ROWS = SEQ + 3;      // 11 staged rows (8 outputs + 3 halo)

union F4 {
    float4 v;
    float f[4];
};

__device__ __forceinline__ void gload_lds16(const float* g, float* l) {
    // async global->LDS, 16B per lane; LDS dest must be wave-uniform base.
    __builtin_amdgcn_global_load_lds(
        (const __attribute__((address_space(1))) void*)g,
        (__attribute__((address_space(3))) void*)l,
        16, 0, 0);
}

__global__ __launch_bounds__(256, 3) void titans_conv(
    const float* __restrict__ x,     // [B,S,C]
    const float* __restrict__ w,     // [C,K]
    const float* __restrict__ bias,  // [C]
    float* __restrict__ out)         // [B,H,S,D]
{
    __shared__ float lds[ROWS * CPB];           // 11 * 4KB = 44KB

    const int t  = threadIdx.x;                 // 0..255
    const int wv = t >> 6;                      // wave 0..3
    const int ln = t & 63;
    const int cb = (int)blockIdx.z * CPB;       // block channel base
    const int c0 = cb + t * 4;                  // this thread's 4 channels
    const int s0 = (int)blockIdx.x * SEQ;
    const int b  = (int)blockIdx.y;

    // per-lane global source within a row; LDS dest is wave-uniform + HW lane*16
    const float* xsrc = x + (size_t)b * Ss * Cc + cb + wv * 256 + ln * 4;

    // ---- weights + bias (L2-hot after first blocks; drained by the barrier) ----
    float wf[4][4], bv[4];
    {
        const float4* wp = (const float4*)(w + (size_t)c0 * Kk);
        F4 u0, u1, u2, u3, ub;
        u0.v = wp[0]; u1.v = wp[1]; u2.v = wp[2]; u3.v = wp[3];
        ub.v = *(const float4*)(bias + c0);
        #pragma unroll
        for (int k = 0; k < 4; ++k) {
            wf[0][k] = u0.f[k]; wf[1][k] = u1.f[k];
            wf[2][k] = u2.f[k]; wf[3][k] = u3.f[k];
        }
        #pragma unroll
        for (int j = 0; j < 4; ++j) bv[j] = ub.f[j];
    }

    // ---- issue ALL row loads async into LDS (11KB in flight per wave) ----
    if (s0 >= 3) {                               // every block except blockIdx.x==0
        #pragma unroll
        for (int r = 0; r < ROWS; ++r)
            gload_lds16(xsrc + (size_t)(s0 - 3 + r) * Cc,
                        &lds[r * CPB + wv * 256]);
    } else {                                     // zero left-pad (block-uniform)
        #pragma unroll
        for (int r = 0; r < 3; ++r)
            *(float4*)&lds[r * CPB + t * 4] = float4{0.f, 0.f, 0.f, 0.f};
        #pragma unroll
        for (int r = 3; r < ROWS; ++r)
            gload_lds16(xsrc + (size_t)(s0 - 3 + r) * Cc,
                        &lds[r * CPB + wv * 256]);
    }

    __syncthreads();   // one vmcnt(0)+lgkmcnt(0)+barrier per block, amortized over 44KB

    // ---- LDS -> regs: contiguous ds_read_b128, each wave reads its own 1KB ----
    F4 rows[ROWS];
    #pragma unroll
    for (int r = 0; r < ROWS; ++r)
        rows[r].v = *(const float4*)&lds[r * CPB + t * 4];

    const int h = c0 >> 7;            // c0 / 128
    const int d = c0 & 127;
    float* orow = out + (((size_t)b * Hh + h) * Ss + s0) * Dd + d;

    #pragma unroll
    for (int i = 0; i < SEQ; ++i) {
        F4 res;
        #pragma unroll
        for (int j = 0; j < 4; ++j) {
            float z = bv[j];
            z = fmaf(wf[j][0], rows[i + 0].f[j], z);
            z = fmaf(wf[j][1], rows[i + 1].f[j], z);
            z = fmaf(wf[j][2], rows[i + 2].f[j], z);
            z = fmaf(wf[j][3], rows[i + 3].f[j], z);
            // silu(z) = z / (1 + exp(-z))
            float e = __expf(-z);
            res.f[j] = z * __builtin_amdgcn_rcpf(1.0f + e);
        }
        *(float4*)(orow + (size_t)i * Dd) = res.v;   // stores never waited on
    }
}

extern "C" void kernel_launch(void* const* d_in, const int* in_sizes, int n_in,
                              void* d_out, int out_size, void* d_ws, size_t ws_size,
                              hipStream_t stream) {
    const float* x    = (const float*)d_in[0];   // hidden_states [B,S,H,D] = [B,S,C]
    const float* w    = (const float*)d_in[1];   // conv_weight [C,K]
    const float* bias = (const float*)d_in[2];   // conv_bias [C]
    float* out        = (float*)d_out;           // [B,H,S,D]

    dim3 grid(Ss / SEQ, Bb, Cc / CPB);  // 512 x 4 x 2 = 4096 blocks
    titans_conv<<<grid, 256, 0, stream>>>(x, w, bias, out);
}